// Round 2
// baseline (82575.342 us; speedup 1.0000x reference)
//
#include <hip/hip_runtime.h>
#include <cstddef>

#define B_SZ   16
#define T_SZ   4096
#define D_SZ   512
#define NSLOT  64
#define NW     16          // workgroups (d-slices) per batch
#define RPW    32          // rows per WG slice (D_SZ / NW)
#define WP     516         // LDS weight row stride (floats, padded)
#define TP     36          // LDS tape row stride (floats, padded)
#define SCALE  0.044194173824159216f   // 1/sqrt(512)

// ---- cross-WG exchange state (module BSS: zero at load; equality-spin makes
// ---- replays safe without any re-init) ----
__device__ float g_ps[B_SZ * NW * NSLOT];   // partial scores [b][w][slot]
__device__ float g_hx[B_SZ * NW * RPW];     // h_new slices   [b][w][j] (flat = [b][d])
__device__ int   g_sf[B_SZ * 32];           // score flags, padded to 128B/batch
__device__ int   g_hf[B_SZ * 32];           // h flags

#define AL(p)    __hip_atomic_load((p),  __ATOMIC_RELAXED, __HIP_MEMORY_SCOPE_AGENT)
#define ALA(p)   __hip_atomic_load((p),  __ATOMIC_ACQUIRE, __HIP_MEMORY_SCOPE_AGENT)
#define AS(p,v)  __hip_atomic_store((p), (v), __ATOMIC_RELAXED, __HIP_MEMORY_SCOPE_AGENT)
#define ASR(p,v) __hip_atomic_store((p), (v), __ATOMIC_RELEASE, __HIP_MEMORY_SCOPE_AGENT)

// ---------------------------------------------------------------------------
// Kernel 1: xw[b][t][d] = x[b][t][:] . W_x[d][:] + b_h[d]  -> h_work_out region
// ---------------------------------------------------------------------------
__global__ __launch_bounds__(256)
void xw_gemm_kernel(const float* __restrict__ X, const float* __restrict__ Wx,
                    const float* __restrict__ bh, float* __restrict__ out)
{
    __shared__ float As[16][68];
    __shared__ float Bs[16][68];
    const int m0 = blockIdx.x * 64;
    const int n0 = blockIdx.y * 64;
    const int tid = threadIdx.x;
    const int tr = tid >> 4, tc = tid & 15;
    const int lrow = tid >> 2;
    const int lkk  = (tid & 3) * 4;

    float acc[4][4] = {};

    for (int k0 = 0; k0 < D_SZ; k0 += 16) {
        float4 av = *(const float4*)(X  + (size_t)(m0 + lrow) * D_SZ + k0 + lkk);
        float4 bv = *(const float4*)(Wx + (size_t)(n0 + lrow) * D_SZ + k0 + lkk);
        As[lkk+0][lrow] = av.x; As[lkk+1][lrow] = av.y;
        As[lkk+2][lrow] = av.z; As[lkk+3][lrow] = av.w;
        Bs[lkk+0][lrow] = bv.x; Bs[lkk+1][lrow] = bv.y;
        Bs[lkk+2][lrow] = bv.z; Bs[lkk+3][lrow] = bv.w;
        __syncthreads();
        #pragma unroll
        for (int kk = 0; kk < 16; ++kk) {
            float a[4], b[4];
            #pragma unroll
            for (int i = 0; i < 4; ++i) a[i] = As[kk][tr*4+i];
            #pragma unroll
            for (int j = 0; j < 4; ++j) b[j] = Bs[kk][tc*4+j];
            #pragma unroll
            for (int i = 0; i < 4; ++i)
                #pragma unroll
                for (int j = 0; j < 4; ++j)
                    acc[i][j] = fmaf(a[i], b[j], acc[i][j]);
        }
        __syncthreads();
    }
    #pragma unroll
    for (int i = 0; i < 4; ++i) {
        const int m = m0 + tr*4 + i;
        const int n = n0 + tc*4;
        float4 o;
        o.x = acc[i][0] + bh[n+0];
        o.y = acc[i][1] + bh[n+1];
        o.z = acc[i][2] + bh[n+2];
        o.w = acc[i][3] + bh[n+3];
        *(float4*)(out + (size_t)m * D_SZ + n) = o;
    }
}

// ---------------------------------------------------------------------------
// Kernel 2: d-sliced recurrence. Grid = B*NW = 256 WGs, 256 threads each.
// WG (b,w) owns rows [32w,32w+32) of W_h/W_write (LDS-resident) and the
// matching tape columns. Two agent-scope flag syncs per step.
// ---------------------------------------------------------------------------
__global__ __launch_bounds__(256, 1)
void recurrence_mw(const float* __restrict__ tape0, const float* __restrict__ h0,
                   const float* __restrict__ W_h, const float* __restrict__ W_w,
                   float* __restrict__ out)
{
    __shared__ float Wh_s[RPW][WP];    // 66,048 B
    __shared__ float Ww_s[RPW][WP];    // 66,048 B
    __shared__ float tp[NSLOT][TP];    //  9,216 B  (tape d-slice, [slot][j])
    __shared__ float hh[D_SZ];         //  2,048 B  (full current h)
    __shared__ float ps_l[NSLOT];
    __shared__ float attn[NSLOT];
    __shared__ float zmv[RPW];
    __shared__ float rp8[8][RPW];

    const int blk = blockIdx.x;
    const int b   = blk >> 4;
    const int w   = blk & (NW - 1);
    const int R0  = w * RPW;
    const int tid = threadIdx.x;
    const int fb  = b * NW;

    // ---- stage weight slices (once per kernel) ----
    for (int i = tid; i < RPW * (D_SZ / 4); i += 256) {
        const int r = i >> 7, c = (i & 127) * 4;
        *(float4*)&Wh_s[r][c] = *(const float4*)(W_h + (size_t)(R0 + r) * D_SZ + c);
        *(float4*)&Ww_s[r][c] = *(const float4*)(W_w + (size_t)(R0 + r) * D_SZ + c);
    }
    // ---- tape slice: tp[s][j] = tape0[b][s][R0+j] ----
    for (int i = tid; i < NSLOT * RPW; i += 256) {
        const int s = i >> 5, j = i & 31;
        tp[s][j] = tape0[((size_t)b * NSLOT + s) * D_SZ + R0 + j];
    }
    for (int i = tid; i < D_SZ; i += 256) hh[i] = h0[(size_t)b * D_SZ + i];
    __syncthreads();

    float* outb = out + (size_t)b * T_SZ * D_SZ;

    const int sA = tid >> 2, qA = tid & 3;    // phase A: 4 threads per slot
    const int g16 = tid >> 4, sj = tid & 15;  // matvec: 16 lanes per row-group
    const int jB = tid & 31, sg = tid >> 5;   // read-partials: 8 slot-groups

    for (int t = 0; t < T_SZ; ++t) {
        // prefetch this WG's xw chunk early (consumed in phase C)
        float xwv = 0.f;
        if (tid < RPW) xwv = outb[(size_t)t * D_SZ + R0 + tid];

        // ---- A1: local partial scores over our 32 d's ----
        {
            float4 t0 = *(const float4*)&tp[sA][qA * 8];
            float4 t1 = *(const float4*)&tp[sA][qA * 8 + 4];
            float4 ha = *(const float4*)&hh[R0 + qA * 8];
            float4 hb = *(const float4*)&hh[R0 + qA * 8 + 4];
            float acc = t0.x*ha.x + t0.y*ha.y + t0.z*ha.z + t0.w*ha.w
                      + t1.x*hb.x + t1.y*hb.y + t1.z*hb.z + t1.w*hb.w;
            acc += __shfl_xor(acc, 1);
            acc += __shfl_xor(acc, 2);
            if (qA == 0) ps_l[sA] = acc;
        }
        __syncthreads();

        // ---- A2: publish partial scores, flag, spin for all slices ----
        if (tid < NSLOT) AS(&g_ps[(fb + w) * NSLOT + tid], ps_l[tid]);
        if (tid == 0)    ASR(&g_sf[b * 32 + w], t + 1);
        if (tid >= 64 && tid < 64 + NW) {
            while (ALA(&g_sf[b * 32 + (tid - 64)]) != t + 1)
                __builtin_amdgcn_s_sleep(1);
        }
        __syncthreads();

        // ---- A3: sum 16 slices' partials -> total scores ----
        {
            float acc = 0.f;
            #pragma unroll
            for (int k = 0; k < 4; ++k)
                acc += AL(&g_ps[(fb + qA * 4 + k) * NSLOT + sA]);
            acc += __shfl_xor(acc, 1);
            acc += __shfl_xor(acc, 2);
            if (qA == 0) ps_l[sA] = acc * SCALE;
        }
        __syncthreads();

        // ---- softmax over 64 slots (wave 0) ----
        if (tid < 64) {
            const float v = ps_l[tid];
            float m = v;
            #pragma unroll
            for (int o = 32; o; o >>= 1) m = fmaxf(m, __shfl_xor(m, o));
            const float e = __expf(v - m);
            float s = e;
            #pragma unroll
            for (int o = 32; o; o >>= 1) s += __shfl_xor(s, o);
            attn[tid] = e / s;
        }
        __syncthreads();

        // ---- B: read partials over our d-slice ----
        {
            float acc = 0.f;
            #pragma unroll
            for (int s8 = 0; s8 < 8; ++s8)
                acc = fmaf(attn[sg * 8 + s8], tp[sg * 8 + s8][jB], acc);
            rp8[sg][jB] = acc;
        }
        // ---- B2: zm rows (g16, g16+16) = W_h[row,:] . h ----
        {
            float4 hr[8];
            #pragma unroll
            for (int i = 0; i < 8; ++i) hr[i] = *(const float4*)&hh[4 * sj + 64 * i];
            #pragma unroll
            for (int p = 0; p < 2; ++p) {
                const int row = g16 + p * 16;
                float acc = 0.f;
                #pragma unroll
                for (int i = 0; i < 8; ++i) {
                    float4 wv = *(const float4*)&Wh_s[row][4 * sj + 64 * i];
                    acc = fmaf(wv.x, hr[i].x, acc);
                    acc = fmaf(wv.y, hr[i].y, acc);
                    acc = fmaf(wv.z, hr[i].z, acc);
                    acc = fmaf(wv.w, hr[i].w, acc);
                }
                acc += __shfl_xor(acc, 1);
                acc += __shfl_xor(acc, 2);
                acc += __shfl_xor(acc, 4);
                acc += __shfl_xor(acc, 8);
                if (sj == 0) zmv[row] = acc;
            }
        }
        __syncthreads();

        // ---- C: h_new for our rows; publish slice; flag; spin ----
        if (tid < RPW) {
            const float rr = rp8[0][tid] + rp8[1][tid] + rp8[2][tid] + rp8[3][tid]
                           + rp8[4][tid] + rp8[5][tid] + rp8[6][tid] + rp8[7][tid];
            const float v = tanhf(zmv[tid] + rr + xwv);
            outb[(size_t)t * D_SZ + R0 + tid] = v;
            AS(&g_hx[(fb + w) * RPW + tid], v);
        }
        if (tid == 0) ASR(&g_hf[b * 32 + w], t + 1);
        if (tid >= 64 && tid < 64 + NW) {
            while (ALA(&g_hf[b * 32 + (tid - 64)]) != t + 1)
                __builtin_amdgcn_s_sleep(1);
        }
        __syncthreads();

        // ---- C2: gather full h_new (g_hx flat = [b][512]) ----
        {
            const int i0 = tid * 2;
            hh[i0]     = AL(&g_hx[fb * RPW + i0]);
            hh[i0 + 1] = AL(&g_hx[fb * RPW + i0 + 1]);
        }
        __syncthreads();

        // ---- D: w_vec rows -> tape slot (our d-slice) ----
        {
            const int slot = t & (NSLOT - 1);
            float4 hr[8];
            #pragma unroll
            for (int i = 0; i < 8; ++i) hr[i] = *(const float4*)&hh[4 * sj + 64 * i];
            #pragma unroll
            for (int p = 0; p < 2; ++p) {
                const int row = g16 + p * 16;
                float acc = 0.f;
                #pragma unroll
                for (int i = 0; i < 8; ++i) {
                    float4 wv = *(const float4*)&Ww_s[row][4 * sj + 64 * i];
                    acc = fmaf(wv.x, hr[i].x, acc);
                    acc = fmaf(wv.y, hr[i].y, acc);
                    acc = fmaf(wv.z, hr[i].z, acc);
                    acc = fmaf(wv.w, hr[i].w, acc);
                }
                acc += __shfl_xor(acc, 1);
                acc += __shfl_xor(acc, 2);
                acc += __shfl_xor(acc, 4);
                acc += __shfl_xor(acc, 8);
                if (sj == 0) tp[slot][row] = acc;
            }
        }
        __syncthreads();
    }

    // ---- epilogue: tape_final slice and last-h slice ----
    float* tout = out + (size_t)B_SZ * T_SZ * D_SZ + (size_t)b * NSLOT * D_SZ;
    for (int i = tid; i < NSLOT * RPW; i += 256) {
        const int s = i >> 5, j = i & 31;
        tout[(size_t)s * D_SZ + R0 + j] = tp[s][j];
    }
    if (tid < RPW) {
        float* lout = out + (size_t)B_SZ * T_SZ * D_SZ
                          + (size_t)B_SZ * NSLOT * D_SZ + (size_t)b * D_SZ;
        lout[R0 + tid] = hh[R0 + tid];
    }
}

// ---------------------------------------------------------------------------
extern "C" void kernel_launch(void* const* d_in, const int* in_sizes, int n_in,
                              void* d_out, int out_size, void* d_ws, size_t ws_size,
                              hipStream_t stream)
{
    const float* x_seq   = (const float*)d_in[0];
    const float* h_tape  = (const float*)d_in[1];
    const float* h_work  = (const float*)d_in[2];
    const float* W_h     = (const float*)d_in[3];
    const float* W_x     = (const float*)d_in[4];
    const float* b_h     = (const float*)d_in[5];
    const float* W_write = (const float*)d_in[6];
    float* out = (float*)d_out;

    dim3 g1(T_SZ * B_SZ / 64, D_SZ / 64);
    xw_gemm_kernel<<<g1, 256, 0, stream>>>(x_seq, W_x, b_h, out);

    recurrence_mw<<<B_SZ * NW, 256, 0, stream>>>(h_tape, h_work, W_h, W_write, out);
}

// Round 3
// 82482.312 us; speedup vs baseline: 1.0011x; 1.0011x over previous
//
#include <hip/hip_runtime.h>
#include <cstddef>

#define B_SZ   16
#define T_SZ   4096
#define D_SZ   512
#define NSLOT  64
#define NW     16          // workgroups (d-slices) per batch
#define RPW    32          // rows per WG slice (D_SZ / NW)
#define WP     516         // LDS weight row stride (floats, padded)
#define TP     36          // LDS tape row stride (floats, padded)
#define FPAD   64          // ints per flag (256B line each — no producer line sharing)
#define SCALE  0.044194173824159216f   // 1/sqrt(512)

// ---- cross-WG exchange state (module BSS: zero at load; equality-spin makes
// ---- replays safe without any re-init) ----
__device__ float g_ps[B_SZ * NW * NSLOT];      // partial scores [b][w][slot] (256B/WG)
__device__ float g_hx[B_SZ * NW * RPW];        // h_new slices   [b][w][j] (flat = [b][d], 128B/WG)
__device__ int   g_sf[B_SZ * NW * FPAD];       // score flags, one 256B line each
__device__ int   g_hf[B_SZ * NW * FPAD];       // h flags, one 256B line each

#define AL(p)    __hip_atomic_load((p),  __ATOMIC_RELAXED, __HIP_MEMORY_SCOPE_AGENT)
#define ALA(p)   __hip_atomic_load((p),  __ATOMIC_ACQUIRE, __HIP_MEMORY_SCOPE_AGENT)
#define AS(p,v)  __hip_atomic_store((p), (v), __ATOMIC_RELAXED, __HIP_MEMORY_SCOPE_AGENT)
#define ASR(p,v) __hip_atomic_store((p), (v), __ATOMIC_RELEASE, __HIP_MEMORY_SCOPE_AGENT)

// ---------------------------------------------------------------------------
// Kernel 1: xw[b][t][d] = x[b][t][:] . W_x[d][:] + b_h[d]  -> h_work_out region
// ---------------------------------------------------------------------------
__global__ __launch_bounds__(256)
void xw_gemm_kernel(const float* __restrict__ X, const float* __restrict__ Wx,
                    const float* __restrict__ bh, float* __restrict__ out)
{
    __shared__ float As[16][68];
    __shared__ float Bs[16][68];
    const int m0 = blockIdx.x * 64;
    const int n0 = blockIdx.y * 64;
    const int tid = threadIdx.x;
    const int tr = tid >> 4, tc = tid & 15;
    const int lrow = tid >> 2;
    const int lkk  = (tid & 3) * 4;

    float acc[4][4] = {};

    for (int k0 = 0; k0 < D_SZ; k0 += 16) {
        float4 av = *(const float4*)(X  + (size_t)(m0 + lrow) * D_SZ + k0 + lkk);
        float4 bv = *(const float4*)(Wx + (size_t)(n0 + lrow) * D_SZ + k0 + lkk);
        As[lkk+0][lrow] = av.x; As[lkk+1][lrow] = av.y;
        As[lkk+2][lrow] = av.z; As[lkk+3][lrow] = av.w;
        Bs[lkk+0][lrow] = bv.x; Bs[lkk+1][lrow] = bv.y;
        Bs[lkk+2][lrow] = bv.z; Bs[lkk+3][lrow] = bv.w;
        __syncthreads();
        #pragma unroll
        for (int kk = 0; kk < 16; ++kk) {
            float a[4], b[4];
            #pragma unroll
            for (int i = 0; i < 4; ++i) a[i] = As[kk][tr*4+i];
            #pragma unroll
            for (int j = 0; j < 4; ++j) b[j] = Bs[kk][tc*4+j];
            #pragma unroll
            for (int i = 0; i < 4; ++i)
                #pragma unroll
                for (int j = 0; j < 4; ++j)
                    acc[i][j] = fmaf(a[i], b[j], acc[i][j]);
        }
        __syncthreads();
    }
    #pragma unroll
    for (int i = 0; i < 4; ++i) {
        const int m = m0 + tr*4 + i;
        const int n = n0 + tc*4;
        float4 o;
        o.x = acc[i][0] + bh[n+0];
        o.y = acc[i][1] + bh[n+1];
        o.z = acc[i][2] + bh[n+2];
        o.w = acc[i][3] + bh[n+3];
        *(float4*)(out + (size_t)m * D_SZ + n) = o;
    }
}

// ---------------------------------------------------------------------------
// Kernel 2: d-sliced recurrence. Grid = B*NW = 256 WGs, 256 threads each.
// blockIdx remapped so a batch's 16 WGs share one XCD (block i -> XCD i%8
// round-robin heuristic): xcd = i&7, j = i>>3, batch = 2*xcd + (j&1), w = j>>1.
// Correctness does not depend on the mapping (G16-safe) — only sync latency.
// ---------------------------------------------------------------------------
__global__ __launch_bounds__(256, 1)
void recurrence_mw(const float* __restrict__ tape0, const float* __restrict__ h0,
                   const float* __restrict__ W_h, const float* __restrict__ W_w,
                   float* __restrict__ out)
{
    __shared__ float Wh_s[RPW][WP];    // 66,048 B
    __shared__ float Ww_s[RPW][WP];    // 66,048 B
    __shared__ float tp[NSLOT][TP];    //  9,216 B  (tape d-slice, [slot][j])
    __shared__ float hh[D_SZ];         //  2,048 B  (full current h)
    __shared__ float ps_l[NSLOT];
    __shared__ float attn[NSLOT];
    __shared__ float zmv[RPW];
    __shared__ float rp8[8][RPW];

    const int blk = blockIdx.x;
    const int xcd = blk & 7;
    const int j   = blk >> 3;
    const int b   = xcd * 2 + (j & 1);
    const int w   = j >> 1;
    const int R0  = w * RPW;
    const int tid = threadIdx.x;
    const int fb  = b * NW;

    // ---- stage weight slices (once per kernel) ----
    for (int i = tid; i < RPW * (D_SZ / 4); i += 256) {
        const int r = i >> 7, c = (i & 127) * 4;
        *(float4*)&Wh_s[r][c] = *(const float4*)(W_h + (size_t)(R0 + r) * D_SZ + c);
        *(float4*)&Ww_s[r][c] = *(const float4*)(W_w + (size_t)(R0 + r) * D_SZ + c);
    }
    // ---- tape slice: tp[s][j] = tape0[b][s][R0+j] ----
    for (int i = tid; i < NSLOT * RPW; i += 256) {
        const int s = i >> 5, jj = i & 31;
        tp[s][jj] = tape0[((size_t)b * NSLOT + s) * D_SZ + R0 + jj];
    }
    for (int i = tid; i < D_SZ; i += 256) hh[i] = h0[(size_t)b * D_SZ + i];
    __syncthreads();

    float* outb = out + (size_t)b * T_SZ * D_SZ;

    const int sA = tid >> 2, qA = tid & 3;    // phase A: 4 threads per slot
    const int g16 = tid >> 4, sj = tid & 15;  // matvec: 16 lanes per row-group
    const int jB = tid & 31, sg = tid >> 5;   // read-partials: 8 slot-groups

    for (int t = 0; t < T_SZ; ++t) {
        // prefetch this WG's xw chunk early (consumed in phase C)
        float xwv = 0.f;
        if (tid < RPW) xwv = outb[(size_t)t * D_SZ + R0 + tid];

        // ---- A1: local partial scores over our 32 d's ----
        {
            float4 t0 = *(const float4*)&tp[sA][qA * 8];
            float4 t1 = *(const float4*)&tp[sA][qA * 8 + 4];
            float4 ha = *(const float4*)&hh[R0 + qA * 8];
            float4 hb = *(const float4*)&hh[R0 + qA * 8 + 4];
            float acc = t0.x*ha.x + t0.y*ha.y + t0.z*ha.z + t0.w*ha.w
                      + t1.x*hb.x + t1.y*hb.y + t1.z*hb.z + t1.w*hb.w;
            acc += __shfl_xor(acc, 1);
            acc += __shfl_xor(acc, 2);
            if (qA == 0) ps_l[sA] = acc;
        }
        __syncthreads();

        // ---- A2: publish partial scores, flag, spin for all slices ----
        if (tid < NSLOT) AS(&g_ps[(fb + w) * NSLOT + tid], ps_l[tid]);
        if (tid == 0)    ASR(&g_sf[(fb + w) * FPAD], t + 1);
        if (tid >= 64 && tid < 64 + NW) {
            while (ALA(&g_sf[(fb + (tid - 64)) * FPAD]) != t + 1)
                __builtin_amdgcn_s_sleep(1);
        }
        __syncthreads();

        // ---- A3: sum 16 slices' partials -> total scores ----
        {
            float acc = 0.f;
            #pragma unroll
            for (int k = 0; k < 4; ++k)
                acc += AL(&g_ps[(fb + qA * 4 + k) * NSLOT + sA]);
            acc += __shfl_xor(acc, 1);
            acc += __shfl_xor(acc, 2);
            if (qA == 0) ps_l[sA] = acc * SCALE;
        }
        __syncthreads();

        // ---- softmax over 64 slots (wave 0) ----
        if (tid < 64) {
            const float v = ps_l[tid];
            float m = v;
            #pragma unroll
            for (int o = 32; o; o >>= 1) m = fmaxf(m, __shfl_xor(m, o));
            const float e = __expf(v - m);
            float s = e;
            #pragma unroll
            for (int o = 32; o; o >>= 1) s += __shfl_xor(s, o);
            attn[tid] = e / s;
        }
        __syncthreads();

        // ---- B: read partials over our d-slice ----
        {
            float acc = 0.f;
            #pragma unroll
            for (int s8 = 0; s8 < 8; ++s8)
                acc = fmaf(attn[sg * 8 + s8], tp[sg * 8 + s8][jB], acc);
            rp8[sg][jB] = acc;
        }
        // ---- B2: zm rows (g16, g16+16) = W_h[row,:] . h ----
        {
            float4 hr[8];
            #pragma unroll
            for (int i = 0; i < 8; ++i) hr[i] = *(const float4*)&hh[4 * sj + 64 * i];
            #pragma unroll
            for (int p = 0; p < 2; ++p) {
                const int row = g16 + p * 16;
                float acc = 0.f;
                #pragma unroll
                for (int i = 0; i < 8; ++i) {
                    float4 wv = *(const float4*)&Wh_s[row][4 * sj + 64 * i];
                    acc = fmaf(wv.x, hr[i].x, acc);
                    acc = fmaf(wv.y, hr[i].y, acc);
                    acc = fmaf(wv.z, hr[i].z, acc);
                    acc = fmaf(wv.w, hr[i].w, acc);
                }
                acc += __shfl_xor(acc, 1);
                acc += __shfl_xor(acc, 2);
                acc += __shfl_xor(acc, 4);
                acc += __shfl_xor(acc, 8);
                if (sj == 0) zmv[row] = acc;
            }
        }
        __syncthreads();

        // ---- C: h_new for our rows; publish slice; flag; spin ----
        if (tid < RPW) {
            const float rr = rp8[0][tid] + rp8[1][tid] + rp8[2][tid] + rp8[3][tid]
                           + rp8[4][tid] + rp8[5][tid] + rp8[6][tid] + rp8[7][tid];
            const float v = tanhf(zmv[tid] + rr + xwv);
            outb[(size_t)t * D_SZ + R0 + tid] = v;
            AS(&g_hx[(fb + w) * RPW + tid], v);
        }
        if (tid == 0) ASR(&g_hf[(fb + w) * FPAD], t + 1);
        if (tid >= 64 && tid < 64 + NW) {
            while (ALA(&g_hf[(fb + (tid - 64)) * FPAD]) != t + 1)
                __builtin_amdgcn_s_sleep(1);
        }
        __syncthreads();

        // ---- C2: gather full h_new (g_hx flat = [b][512]) ----
        {
            const int i0 = tid * 2;
            hh[i0]     = AL(&g_hx[fb * RPW + i0]);
            hh[i0 + 1] = AL(&g_hx[fb * RPW + i0 + 1]);
        }
        __syncthreads();

        // ---- D: w_vec rows -> tape slot (our d-slice) ----
        {
            const int slot = t & (NSLOT - 1);
            float4 hr[8];
            #pragma unroll
            for (int i = 0; i < 8; ++i) hr[i] = *(const float4*)&hh[4 * sj + 64 * i];
            #pragma unroll
            for (int p = 0; p < 2; ++p) {
                const int row = g16 + p * 16;
                float acc = 0.f;
                #pragma unroll
                for (int i = 0; i < 8; ++i) {
                    float4 wv = *(const float4*)&Ww_s[row][4 * sj + 64 * i];
                    acc = fmaf(wv.x, hr[i].x, acc);
                    acc = fmaf(wv.y, hr[i].y, acc);
                    acc = fmaf(wv.z, hr[i].z, acc);
                    acc = fmaf(wv.w, hr[i].w, acc);
                }
                acc += __shfl_xor(acc, 1);
                acc += __shfl_xor(acc, 2);
                acc += __shfl_xor(acc, 4);
                acc += __shfl_xor(acc, 8);
                if (sj == 0) tp[slot][row] = acc;
            }
        }
        __syncthreads();
    }

    // ---- epilogue: tape_final slice and last-h slice ----
    float* tout = out + (size_t)B_SZ * T_SZ * D_SZ + (size_t)b * NSLOT * D_SZ;
    for (int i = tid; i < NSLOT * RPW; i += 256) {
        const int s = i >> 5, jj = i & 31;
        tout[(size_t)s * D_SZ + R0 + jj] = tp[s][jj];
    }
    if (tid < RPW) {
        float* lout = out + (size_t)B_SZ * T_SZ * D_SZ
                          + (size_t)B_SZ * NSLOT * D_SZ + (size_t)b * D_SZ;
        lout[R0 + tid] = hh[R0 + tid];
    }
}

// ---------------------------------------------------------------------------
extern "C" void kernel_launch(void* const* d_in, const int* in_sizes, int n_in,
                              void* d_out, int out_size, void* d_ws, size_t ws_size,
                              hipStream_t stream)
{
    const float* x_seq   = (const float*)d_in[0];
    const float* h_tape  = (const float*)d_in[1];
    const float* h_work  = (const float*)d_in[2];
    const float* W_h     = (const float*)d_in[3];
    const float* W_x     = (const float*)d_in[4];
    const float* b_h     = (const float*)d_in[5];
    const float* W_write = (const float*)d_in[6];
    float* out = (float*)d_out;

    dim3 g1(T_SZ * B_SZ / 64, D_SZ / 64);
    xw_gemm_kernel<<<g1, 256, 0, stream>>>(x_seq, W_x, b_h, out);

    recurrence_mw<<<B_SZ * NW, 256, 0, stream>>>(h_tape, h_work, W_h, W_write, out);
}

// Round 5
// 18528.004 us; speedup vs baseline: 4.4568x; 4.4518x over previous
//
#include <hip/hip_runtime.h>
#include <cstddef>

#define B_SZ   16
#define T_SZ   4096
#define D_SZ   512
#define NSLOT  64
#define NW     16          // workgroups (d-slices) per batch
#define RPW    32          // rows per WG slice (D_SZ / NW)
#define WP     516         // LDS weight row stride (floats, padded)
#define TP     36          // LDS tape row stride (floats, padded)
#define FPAD   64          // ints per flag (256B line each)
#define SCALE  0.044194173824159216f   // 1/sqrt(512)

// ---- cross-WG exchange state (module BSS: zero at load; equality-spin makes
// ---- replays safe without any re-init) ----
__device__ __align__(16) float g_ps[B_SZ * NW * NSLOT];  // partial scores [b][w][slot]
__device__ __align__(16) float g_hx[B_SZ * NW * RPW];    // h_new slices (flat = [b][d])
__device__ int g_sf[B_SZ * NW * FPAD];                   // score flags, 256B apart
__device__ int g_hf[B_SZ * NW * FPAD];                   // h flags, 256B apart

// Relaxed agent-scope atomics ONLY — no acquire/release: on gfx950 those lower
// to buffer_inv / buffer_wbl2 (full L2 maintenance) which cost ~10us per sync.
// Ordering is done manually: producer does s_waitcnt vmcnt(0) between data
// stores and flag store (same wave); consumer orders flag->data by control
// dependency + __syncthreads.
#define AL(p)    __hip_atomic_load((p),  __ATOMIC_RELAXED, __HIP_MEMORY_SCOPE_AGENT)
#define AS(p,v)  __hip_atomic_store((p), (v), __ATOMIC_RELAXED, __HIP_MEMORY_SCOPE_AGENT)
#define VMCNT0() __asm__ __volatile__("s_waitcnt vmcnt(0)" ::: "memory")

// ---------------------------------------------------------------------------
// Kernel 1: xw[b][t][d] = x[b][t][:] . W_x[d][:] + b_h[d]  -> h_work_out region
// ---------------------------------------------------------------------------
__global__ __launch_bounds__(256)
void xw_gemm_kernel(const float* __restrict__ X, const float* __restrict__ Wx,
                    const float* __restrict__ bh, float* __restrict__ out)
{
    __shared__ float As[16][68];
    __shared__ float Bs[16][68];
    const int m0 = blockIdx.x * 64;
    const int n0 = blockIdx.y * 64;
    const int tid = threadIdx.x;
    const int tr = tid >> 4, tc = tid & 15;
    const int lrow = tid >> 2;
    const int lkk  = (tid & 3) * 4;

    float acc[4][4] = {};

    for (int k0 = 0; k0 < D_SZ; k0 += 16) {
        float4 av = *(const float4*)(X  + (size_t)(m0 + lrow) * D_SZ + k0 + lkk);
        float4 bv = *(const float4*)(Wx + (size_t)(n0 + lrow) * D_SZ + k0 + lkk);
        As[lkk+0][lrow] = av.x; As[lkk+1][lrow] = av.y;
        As[lkk+2][lrow] = av.z; As[lkk+3][lrow] = av.w;
        Bs[lkk+0][lrow] = bv.x; Bs[lkk+1][lrow] = bv.y;
        Bs[lkk+2][lrow] = bv.z; Bs[lkk+3][lrow] = bv.w;
        __syncthreads();
        #pragma unroll
        for (int kk = 0; kk < 16; ++kk) {
            float a[4], b[4];
            #pragma unroll
            for (int i = 0; i < 4; ++i) a[i] = As[kk][tr*4+i];
            #pragma unroll
            for (int j = 0; j < 4; ++j) b[j] = Bs[kk][tc*4+j];
            #pragma unroll
            for (int i = 0; i < 4; ++i)
                #pragma unroll
                for (int j = 0; j < 4; ++j)
                    acc[i][j] = fmaf(a[i], b[j], acc[i][j]);
        }
        __syncthreads();
    }
    #pragma unroll
    for (int i = 0; i < 4; ++i) {
        const int m = m0 + tr*4 + i;
        const int n = n0 + tc*4;
        float4 o;
        o.x = acc[i][0] + bh[n+0];
        o.y = acc[i][1] + bh[n+1];
        o.z = acc[i][2] + bh[n+2];
        o.w = acc[i][3] + bh[n+3];
        *(float4*)(out + (size_t)m * D_SZ + n) = o;
    }
}

// ---------------------------------------------------------------------------
// Kernel 2: d-sliced recurrence. Grid = B*NW = 256 WGs, 256 threads each.
// Weights LDS-resident; two relaxed-atomic flag syncs per step; W_h matvec
// overlapped with the score-sync window.
// ---------------------------------------------------------------------------
__global__ __launch_bounds__(256, 1)
void recurrence_mw(const float* __restrict__ tape0, const float* __restrict__ h0,
                   const float* __restrict__ W_h, const float* __restrict__ W_w,
                   float* __restrict__ out)
{
    __shared__ float Wh_s[RPW][WP];
    __shared__ float Ww_s[RPW][WP];
    __shared__ float tp[NSLOT][TP];
    __shared__ float hh[D_SZ];
    __shared__ float ps_l[NSLOT];
    __shared__ float attn[NSLOT];
    __shared__ float zmv[RPW];
    __shared__ float rp8[8][RPW];

    const int blk = blockIdx.x;
    const int xcd = blk & 7;
    const int jj0 = blk >> 3;
    const int b   = xcd * 2 + (jj0 & 1);
    const int w   = jj0 >> 1;
    const int R0  = w * RPW;
    const int tid = threadIdx.x;
    const int fb  = b * NW;

    for (int i = tid; i < RPW * (D_SZ / 4); i += 256) {
        const int r = i >> 7, c = (i & 127) * 4;
        *(float4*)&Wh_s[r][c] = *(const float4*)(W_h + (size_t)(R0 + r) * D_SZ + c);
        *(float4*)&Ww_s[r][c] = *(const float4*)(W_w + (size_t)(R0 + r) * D_SZ + c);
    }
    for (int i = tid; i < NSLOT * RPW; i += 256) {
        const int s = i >> 5, jc = i & 31;
        tp[s][jc] = tape0[((size_t)b * NSLOT + s) * D_SZ + R0 + jc];
    }
    for (int i = tid; i < D_SZ; i += 256) hh[i] = h0[(size_t)b * D_SZ + i];
    __syncthreads();

    float* outb = out + (size_t)b * T_SZ * D_SZ;

    const int sA = tid >> 2, qA = tid & 3;    // 4 threads per slot (scores)
    const int g16 = tid >> 4, sj = tid & 15;  // matvec: 16 lanes per row-group
    const int jB = tid & 31, sg = tid >> 5;   // read-partials: 8 slot-groups

    for (int t = 0; t < T_SZ; ++t) {
        float xwv = 0.f;
        if (tid < RPW) xwv = outb[(size_t)t * D_SZ + R0 + tid];

        // ---- A1: local partial scores over our 32 d's ----
        {
            float4 t0 = *(const float4*)&tp[sA][qA * 8];
            float4 t1 = *(const float4*)&tp[sA][qA * 8 + 4];
            float4 ha = *(const float4*)&hh[R0 + qA * 8];
            float4 hb = *(const float4*)&hh[R0 + qA * 8 + 4];
            float acc = t0.x*ha.x + t0.y*ha.y + t0.z*ha.z + t0.w*ha.w
                      + t1.x*hb.x + t1.y*hb.y + t1.z*hb.z + t1.w*hb.w;
            acc += __shfl_xor(acc, 1);
            acc += __shfl_xor(acc, 2);
            if (qA == 0) ps_l[sA] = acc;
        }
        __syncthreads();

        // ---- A2: publish partial scores (wave 0), data->flag ordered by vmcnt ----
        if (tid < NSLOT) AS(&g_ps[(fb + w) * NSLOT + tid], ps_l[tid]);
        if (tid == 0) { VMCNT0(); AS(&g_sf[(fb + w) * FPAD], t + 1); }

        // ---- B2: zm = W_h . h — overlaps peers' publish latency ----
        {
            float4 hr[8];
            #pragma unroll
            for (int i = 0; i < 8; ++i) hr[i] = *(const float4*)&hh[4 * sj + 64 * i];
            #pragma unroll
            for (int p = 0; p < 2; ++p) {
                const int row = g16 + p * 16;
                float acc = 0.f;
                #pragma unroll
                for (int i = 0; i < 8; ++i) {
                    float4 wv = *(const float4*)&Wh_s[row][4 * sj + 64 * i];
                    acc = fmaf(wv.x, hr[i].x, acc);
                    acc = fmaf(wv.y, hr[i].y, acc);
                    acc = fmaf(wv.z, hr[i].z, acc);
                    acc = fmaf(wv.w, hr[i].w, acc);
                }
                acc += __shfl_xor(acc, 1);
                acc += __shfl_xor(acc, 2);
                acc += __shfl_xor(acc, 4);
                acc += __shfl_xor(acc, 8);
                if (sj == 0) zmv[row] = acc;
            }
        }

        // ---- spin for all slices' score flags (relaxed; wave 1 lanes 0-15) ----
        if (tid >= 64 && tid < 64 + NW) {
            while (AL(&g_sf[(fb + (tid - 64)) * FPAD]) != t + 1)
                __builtin_amdgcn_s_sleep(1);
        }
        __syncthreads();

        // ---- A3: sum 16 slices' partials -> total scores ----
        {
            float acc = 0.f;
            #pragma unroll
            for (int k = 0; k < 4; ++k)
                acc += AL(&g_ps[(fb + qA * 4 + k) * NSLOT + sA]);
            acc += __shfl_xor(acc, 1);
            acc += __shfl_xor(acc, 2);
            if (qA == 0) ps_l[sA] = acc * SCALE;
        }
        __syncthreads();

        // ---- softmax over 64 slots (wave 0) ----
        if (tid < 64) {
            const float v = ps_l[tid];
            float m = v;
            #pragma unroll
            for (int o = 32; o; o >>= 1) m = fmaxf(m, __shfl_xor(m, o));
            const float e = __expf(v - m);
            float s = e;
            #pragma unroll
            for (int o = 32; o; o >>= 1) s += __shfl_xor(s, o);
            attn[tid] = e / s;
        }
        __syncthreads();

        // ---- B: read partials over our d-slice ----
        {
            float acc = 0.f;
            #pragma unroll
            for (int s8 = 0; s8 < 8; ++s8)
                acc = fmaf(attn[sg * 8 + s8], tp[sg * 8 + s8][jB], acc);
            rp8[sg][jB] = acc;
        }
        __syncthreads();

        // ---- C: h_new for our rows; publish slice; vmcnt-ordered flag ----
        if (tid < RPW) {
            const float rr = rp8[0][tid] + rp8[1][tid] + rp8[2][tid] + rp8[3][tid]
                           + rp8[4][tid] + rp8[5][tid] + rp8[6][tid] + rp8[7][tid];
            const float v = tanhf(zmv[tid] + rr + xwv);
            outb[(size_t)t * D_SZ + R0 + tid] = v;
            AS(&g_hx[(fb + w) * RPW + tid], v);
        }
        if (tid == 0) { VMCNT0(); AS(&g_hf[(fb + w) * FPAD], t + 1); }
        if (tid >= 64 && tid < 64 + NW) {
            while (AL(&g_hf[(fb + (tid - 64)) * FPAD]) != t + 1)
                __builtin_amdgcn_s_sleep(1);
        }
        __syncthreads();

        // ---- C2: gather full h_new (two 4B relaxed atomic loads per thread) ----
        {
            const int i0 = tid * 2;
            hh[i0]     = AL(&g_hx[fb * RPW + i0]);
            hh[i0 + 1] = AL(&g_hx[fb * RPW + i0 + 1]);
        }
        __syncthreads();

        // ---- D: w_vec rows -> tape slot ----
        {
            const int slot = t & (NSLOT - 1);
            float4 hr[8];
            #pragma unroll
            for (int i = 0; i < 8; ++i) hr[i] = *(const float4*)&hh[4 * sj + 64 * i];
            #pragma unroll
            for (int p = 0; p < 2; ++p) {
                const int row = g16 + p * 16;
                float acc = 0.f;
                #pragma unroll
                for (int i = 0; i < 8; ++i) {
                    float4 wv = *(const float4*)&Ww_s[row][4 * sj + 64 * i];
                    acc = fmaf(wv.x, hr[i].x, acc);
                    acc = fmaf(wv.y, hr[i].y, acc);
                    acc = fmaf(wv.z, hr[i].z, acc);
                    acc = fmaf(wv.w, hr[i].w, acc);
                }
                acc += __shfl_xor(acc, 1);
                acc += __shfl_xor(acc, 2);
                acc += __shfl_xor(acc, 4);
                acc += __shfl_xor(acc, 8);
                if (sj == 0) tp[slot][row] = acc;
            }
        }
        __syncthreads();
    }

    // ---- epilogue ----
    float* tout = out + (size_t)B_SZ * T_SZ * D_SZ + (size_t)b * NSLOT * D_SZ;
    for (int i = tid; i < NSLOT * RPW; i += 256) {
        const int s = i >> 5, jc = i & 31;
        tout[(size_t)s * D_SZ + R0 + jc] = tp[s][jc];
    }
    if (tid < RPW) {
        float* lout = out + (size_t)B_SZ * T_SZ * D_SZ
                          + (size_t)B_SZ * NSLOT * D_SZ + (size_t)b * D_SZ;
        lout[R0 + tid] = hh[R0 + tid];
    }
}

// ---------------------------------------------------------------------------
extern "C" void kernel_launch(void* const* d_in, const int* in_sizes, int n_in,
                              void* d_out, int out_size, void* d_ws, size_t ws_size,
                              hipStream_t stream)
{
    const float* x_seq   = (const float*)d_in[0];
    const float* h_tape  = (const float*)d_in[1];
    const float* h_work  = (const float*)d_in[2];
    const float* W_h     = (const float*)d_in[3];
    const float* W_x     = (const float*)d_in[4];
    const float* b_h     = (const float*)d_in[5];
    const float* W_write = (const float*)d_in[6];
    float* out = (float*)d_out;

    dim3 g1(T_SZ * B_SZ / 64, D_SZ / 64);
    xw_gemm_kernel<<<g1, 256, 0, stream>>>(x_seq, W_x, b_h, out);

    recurrence_mw<<<B_SZ * NW, 256, 0, stream>>>(h_tape, h_work, W_h, W_write, out);
}

// Round 6
// 17549.086 us; speedup vs baseline: 4.7054x; 1.0558x over previous
//
#include <hip/hip_runtime.h>
#include <cstddef>

#define B_SZ   16
#define T_SZ   4096
#define D_SZ   512
#define NSLOT  64
#define NW     16          // workgroups (d-slices) per batch
#define RPW    32          // rows per WG slice (D_SZ / NW)
#define WP     516         // LDS weight row stride (floats, padded)
#define TP     36          // LDS tape row stride (floats, padded)
#define SCALE  0.044194173824159216f   // 1/sqrt(512)

// ---- cross-WG exchange: self-tagged (float,tag) 8B pairs. Consumer polls the
// ---- datum itself until tag==t+1 — no flags, no vmcnt, no fences. Producers
// ---- zero their own slots at kernel start (same-thread ordering) so tag
// ---- history per address is {0,1,...}, making equality polls replay-safe.
__device__ __align__(8) unsigned long long g_ps2[B_SZ * NW * NSLOT]; // partial scores
__device__ __align__(8) unsigned long long g_hx2[B_SZ * D_SZ];      // h_new by [b][d]

#define AL(p)    __hip_atomic_load((p),  __ATOMIC_RELAXED, __HIP_MEMORY_SCOPE_AGENT)
#define AS(p,v)  __hip_atomic_store((p), (v), __ATOMIC_RELAXED, __HIP_MEMORY_SCOPE_AGENT)

__device__ __forceinline__ unsigned long long pk(float v, unsigned tag) {
    return ((unsigned long long)tag << 32) | (unsigned long long)__float_as_uint(v);
}

// ---------------------------------------------------------------------------
// Kernel 1: xw[b][t][d] = x[b][t][:] . W_x[d][:] + b_h[d]  -> h_work_out region
// ---------------------------------------------------------------------------
__global__ __launch_bounds__(256)
void xw_gemm_kernel(const float* __restrict__ X, const float* __restrict__ Wx,
                    const float* __restrict__ bh, float* __restrict__ out)
{
    __shared__ float As[16][68];
    __shared__ float Bs[16][68];
    const int m0 = blockIdx.x * 64;
    const int n0 = blockIdx.y * 64;
    const int tid = threadIdx.x;
    const int tr = tid >> 4, tc = tid & 15;
    const int lrow = tid >> 2;
    const int lkk  = (tid & 3) * 4;

    float acc[4][4] = {};

    for (int k0 = 0; k0 < D_SZ; k0 += 16) {
        float4 av = *(const float4*)(X  + (size_t)(m0 + lrow) * D_SZ + k0 + lkk);
        float4 bv = *(const float4*)(Wx + (size_t)(n0 + lrow) * D_SZ + k0 + lkk);
        As[lkk+0][lrow] = av.x; As[lkk+1][lrow] = av.y;
        As[lkk+2][lrow] = av.z; As[lkk+3][lrow] = av.w;
        Bs[lkk+0][lrow] = bv.x; Bs[lkk+1][lrow] = bv.y;
        Bs[lkk+2][lrow] = bv.z; Bs[lkk+3][lrow] = bv.w;
        __syncthreads();
        #pragma unroll
        for (int kk = 0; kk < 16; ++kk) {
            float a[4], b[4];
            #pragma unroll
            for (int i = 0; i < 4; ++i) a[i] = As[kk][tr*4+i];
            #pragma unroll
            for (int j = 0; j < 4; ++j) b[j] = Bs[kk][tc*4+j];
            #pragma unroll
            for (int i = 0; i < 4; ++i)
                #pragma unroll
                for (int j = 0; j < 4; ++j)
                    acc[i][j] = fmaf(a[i], b[j], acc[i][j]);
        }
        __syncthreads();
    }
    #pragma unroll
    for (int i = 0; i < 4; ++i) {
        const int m = m0 + tr*4 + i;
        const int n = n0 + tc*4;
        float4 o;
        o.x = acc[i][0] + bh[n+0];
        o.y = acc[i][1] + bh[n+1];
        o.z = acc[i][2] + bh[n+2];
        o.w = acc[i][3] + bh[n+3];
        *(float4*)(out + (size_t)m * D_SZ + n) = o;
    }
}

// ---------------------------------------------------------------------------
// Kernel 2: d-sliced recurrence, self-tagged-pair sync. Grid = 256 WGs.
// ---------------------------------------------------------------------------
__global__ __launch_bounds__(256, 1)
void recurrence_mw(const float* __restrict__ tape0, const float* __restrict__ h0,
                   const float* __restrict__ W_h, const float* __restrict__ W_w,
                   float* __restrict__ out)
{
    __shared__ float Wh_s[RPW][WP];
    __shared__ float Ww_s[RPW][WP];
    __shared__ float tp[NSLOT][TP];
    __shared__ float hh[D_SZ];
    __shared__ float ps_l[NSLOT];
    __shared__ float attn[NSLOT];
    __shared__ float zmv[RPW];
    __shared__ float rp8[8][RPW];

    const int blk = blockIdx.x;
    const int xcd = blk & 7;
    const int jj0 = blk >> 3;
    const int b   = xcd * 2 + (jj0 & 1);
    const int w   = jj0 >> 1;
    const int R0  = w * RPW;
    const int tid = threadIdx.x;
    const int fb  = b * NW;

    // ---- zero own pair slots (replay safety; same-thread ordering) ----
    if (tid < NSLOT) AS(&g_ps2[(size_t)(fb + w) * NSLOT + tid], 0ULL);
    if (tid < RPW)   AS(&g_hx2[(size_t)b * D_SZ + R0 + tid], 0ULL);

    for (int i = tid; i < RPW * (D_SZ / 4); i += 256) {
        const int r = i >> 7, c = (i & 127) * 4;
        *(float4*)&Wh_s[r][c] = *(const float4*)(W_h + (size_t)(R0 + r) * D_SZ + c);
        *(float4*)&Ww_s[r][c] = *(const float4*)(W_w + (size_t)(R0 + r) * D_SZ + c);
    }
    for (int i = tid; i < NSLOT * RPW; i += 256) {
        const int s = i >> 5, jc = i & 31;
        tp[s][jc] = tape0[((size_t)b * NSLOT + s) * D_SZ + R0 + jc];
    }
    for (int i = tid; i < D_SZ; i += 256) hh[i] = h0[(size_t)b * D_SZ + i];
    __syncthreads();

    float* outb = out + (size_t)b * T_SZ * D_SZ;

    const int sA = tid >> 2, qA = tid & 3;    // 4 threads per slot (scores)
    const int g16 = tid >> 4, sj = tid & 15;  // matvec: 16 lanes per row-group
    const int jB = tid & 31, sg = tid >> 5;   // read-partials: 8 slot-groups

    for (int t = 0; t < T_SZ; ++t) {
        const unsigned tg = (unsigned)(t + 1);
        float xwv = 0.f;
        if (tid < RPW) xwv = outb[(size_t)t * D_SZ + R0 + tid];

        // ---- A1: local partial scores over our 32 d's ----
        {
            float4 t0 = *(const float4*)&tp[sA][qA * 8];
            float4 t1 = *(const float4*)&tp[sA][qA * 8 + 4];
            float4 ha = *(const float4*)&hh[R0 + qA * 8];
            float4 hb = *(const float4*)&hh[R0 + qA * 8 + 4];
            float acc = t0.x*ha.x + t0.y*ha.y + t0.z*ha.z + t0.w*ha.w
                      + t1.x*hb.x + t1.y*hb.y + t1.z*hb.z + t1.w*hb.w;
            acc += __shfl_xor(acc, 1);
            acc += __shfl_xor(acc, 2);
            if (qA == 0) ps_l[sA] = acc;
        }
        __syncthreads();

        // ---- A2: publish tagged partial scores (no fence, no flag) ----
        if (tid < NSLOT)
            AS(&g_ps2[(size_t)(fb + w) * NSLOT + tid], pk(ps_l[tid], tg));

        // ---- B2: zm = W_h . h — overlaps score propagation ----
        {
            float4 hr[8];
            #pragma unroll
            for (int i = 0; i < 8; ++i) hr[i] = *(const float4*)&hh[4 * sj + 64 * i];
            #pragma unroll
            for (int p = 0; p < 2; ++p) {
                const int row = g16 + p * 16;
                float acc = 0.f;
                #pragma unroll
                for (int i = 0; i < 8; ++i) {
                    float4 wv = *(const float4*)&Wh_s[row][4 * sj + 64 * i];
                    acc = fmaf(wv.x, hr[i].x, acc);
                    acc = fmaf(wv.y, hr[i].y, acc);
                    acc = fmaf(wv.z, hr[i].z, acc);
                    acc = fmaf(wv.w, hr[i].w, acc);
                }
                acc += __shfl_xor(acc, 1);
                acc += __shfl_xor(acc, 2);
                acc += __shfl_xor(acc, 4);
                acc += __shfl_xor(acc, 8);
                if (sj == 0) zmv[row] = acc;
            }
        }

        // ---- poll 4 score pairs (w' = 4*qA..4*qA+3, slot sA); sum on match ----
        {
            const unsigned long long* pp = &g_ps2[(size_t)(fb + qA * 4) * NSLOT + sA];
            unsigned long long v0, v1, v2, v3;
            for (;;) {
                v0 = AL(pp + 0 * NSLOT); v1 = AL(pp + 1 * NSLOT);
                v2 = AL(pp + 2 * NSLOT); v3 = AL(pp + 3 * NSLOT);
                if ((unsigned)(v0 >> 32) == tg && (unsigned)(v1 >> 32) == tg &&
                    (unsigned)(v2 >> 32) == tg && (unsigned)(v3 >> 32) == tg) break;
                __builtin_amdgcn_s_sleep(1);
            }
            float acc = __uint_as_float((unsigned)v0) + __uint_as_float((unsigned)v1)
                      + __uint_as_float((unsigned)v2) + __uint_as_float((unsigned)v3);
            acc += __shfl_xor(acc, 1);
            acc += __shfl_xor(acc, 2);
            if (qA == 0) ps_l[sA] = acc * SCALE;
        }
        __syncthreads();

        // ---- softmax over 64 slots (wave 0) ----
        if (tid < 64) {
            const float v = ps_l[tid];
            float m = v;
            #pragma unroll
            for (int o = 32; o; o >>= 1) m = fmaxf(m, __shfl_xor(m, o));
            const float e = __expf(v - m);
            float s = e;
            #pragma unroll
            for (int o = 32; o; o >>= 1) s += __shfl_xor(s, o);
            attn[tid] = e / s;
        }
        __syncthreads();

        // ---- B: read partials over our d-slice ----
        {
            float acc = 0.f;
            #pragma unroll
            for (int s8 = 0; s8 < 8; ++s8)
                acc = fmaf(attn[sg * 8 + s8], tp[sg * 8 + s8][jB], acc);
            rp8[sg][jB] = acc;
        }
        __syncthreads();

        // ---- C: h_new own rows; publish tagged pairs (no fence, no flag) ----
        if (tid < RPW) {
            const float rr = rp8[0][tid] + rp8[1][tid] + rp8[2][tid] + rp8[3][tid]
                           + rp8[4][tid] + rp8[5][tid] + rp8[6][tid] + rp8[7][tid];
            const float v = tanhf(zmv[tid] + rr + xwv);
            outb[(size_t)t * D_SZ + R0 + tid] = v;
            AS(&g_hx2[(size_t)b * D_SZ + R0 + tid], pk(v, tg));
        }

        // ---- hoist D's weight rows into regs (h-independent) during h-poll ----
        float4 wv0[8], wv1[8];
        #pragma unroll
        for (int i = 0; i < 8; ++i) {
            wv0[i] = *(const float4*)&Ww_s[g16][4 * sj + 64 * i];
            wv1[i] = *(const float4*)&Ww_s[g16 + 16][4 * sj + 64 * i];
        }

        // ---- C2: poll own two h pairs, fill hh ----
        {
            const int d0 = tid * 2;
            const unsigned long long* hp = &g_hx2[(size_t)b * D_SZ + d0];
            unsigned long long v0, v1;
            for (;;) {
                v0 = AL(hp); v1 = AL(hp + 1);
                if ((unsigned)(v0 >> 32) == tg && (unsigned)(v1 >> 32) == tg) break;
                __builtin_amdgcn_s_sleep(1);
            }
            hh[d0]     = __uint_as_float((unsigned)v0);
            hh[d0 + 1] = __uint_as_float((unsigned)v1);
        }
        __syncthreads();

        // ---- D: w_vec rows -> tape slot ----
        {
            const int slot = t & (NSLOT - 1);
            float4 hr[8];
            #pragma unroll
            for (int i = 0; i < 8; ++i) hr[i] = *(const float4*)&hh[4 * sj + 64 * i];
            float a0 = 0.f, a1 = 0.f;
            #pragma unroll
            for (int i = 0; i < 8; ++i) {
                a0 = fmaf(wv0[i].x, hr[i].x, a0);
                a0 = fmaf(wv0[i].y, hr[i].y, a0);
                a0 = fmaf(wv0[i].z, hr[i].z, a0);
                a0 = fmaf(wv0[i].w, hr[i].w, a0);
                a1 = fmaf(wv1[i].x, hr[i].x, a1);
                a1 = fmaf(wv1[i].y, hr[i].y, a1);
                a1 = fmaf(wv1[i].z, hr[i].z, a1);
                a1 = fmaf(wv1[i].w, hr[i].w, a1);
            }
            a0 += __shfl_xor(a0, 1); a1 += __shfl_xor(a1, 1);
            a0 += __shfl_xor(a0, 2); a1 += __shfl_xor(a1, 2);
            a0 += __shfl_xor(a0, 4); a1 += __shfl_xor(a1, 4);
            a0 += __shfl_xor(a0, 8); a1 += __shfl_xor(a1, 8);
            if (sj == 0) {
                tp[slot][g16]      = a0;
                tp[slot][g16 + 16] = a1;
            }
        }
        __syncthreads();
    }

    // ---- epilogue: tape slice + last-h slice ----
    float* tout = out + (size_t)B_SZ * T_SZ * D_SZ + (size_t)b * NSLOT * D_SZ;
    for (int i = tid; i < NSLOT * RPW; i += 256) {
        const int s = i >> 5, jc = i & 31;
        tout[(size_t)s * D_SZ + R0 + jc] = tp[s][jc];
    }
    if (tid < RPW) {
        float* lout = out + (size_t)B_SZ * T_SZ * D_SZ
                          + (size_t)B_SZ * NSLOT * D_SZ + (size_t)b * D_SZ;
        lout[R0 + tid] = hh[R0 + tid];
    }
}

// ---------------------------------------------------------------------------
extern "C" void kernel_launch(void* const* d_in, const int* in_sizes, int n_in,
                              void* d_out, int out_size, void* d_ws, size_t ws_size,
                              hipStream_t stream)
{
    const float* x_seq   = (const float*)d_in[0];
    const float* h_tape  = (const float*)d_in[1];
    const float* h_work  = (const float*)d_in[2];
    const float* W_h     = (const float*)d_in[3];
    const float* W_x     = (const float*)d_in[4];
    const float* b_h     = (const float*)d_in[5];
    const float* W_write = (const float*)d_in[6];
    float* out = (float*)d_out;

    dim3 g1(T_SZ * B_SZ / 64, D_SZ / 64);
    xw_gemm_kernel<<<g1, 256, 0, stream>>>(x_seq, W_x, b_h, out);

    recurrence_mw<<<B_SZ * NW, 256, 0, stream>>>(h_tape, h_work, W_h, W_write, out);
}

// Round 7
// 15881.754 us; speedup vs baseline: 5.1994x; 1.1050x over previous
//
#include <hip/hip_runtime.h>
#include <cstddef>

#define B_SZ   16
#define T_SZ   4096
#define D_SZ   512
#define NSLOT  64
#define NW     16          // workgroups (d-slices) per batch
#define RPW    32          // rows per WG slice (D_SZ / NW)
#define TP     36          // LDS tape row stride (floats, padded)
#define SCALE  0.044194173824159216f   // 1/sqrt(512)

// ---- cross-WG exchange: self-tagged (float,tag) 8B pairs. Consumer polls the
// ---- datum itself until tag==t+1 — no flags, no vmcnt, no fences. Stale tags
// ---- from a finished replay are always 4096 (or 0 on first run), which can
// ---- never equal the expected tag at the time it is polled (see R5 analysis).
__device__ __align__(8) unsigned long long g_ps2[B_SZ * NW * NSLOT]; // partial scores
__device__ __align__(8) unsigned long long g_hx2[B_SZ * D_SZ];      // h_new by [b][d]

#define AL(p)    __hip_atomic_load((p),  __ATOMIC_RELAXED, __HIP_MEMORY_SCOPE_AGENT)
#define AS(p,v)  __hip_atomic_store((p), (v), __ATOMIC_RELAXED, __HIP_MEMORY_SCOPE_AGENT)

__device__ __forceinline__ unsigned long long pk(float v, unsigned tag) {
    return ((unsigned long long)tag << 32) | (unsigned long long)__float_as_uint(v);
}

// ---------------------------------------------------------------------------
// Kernel 1: xw[b][t][d] = x[b][t][:] . W_x[d][:] + b_h[d]  -> h_work_out region
// ---------------------------------------------------------------------------
__global__ __launch_bounds__(256)
void xw_gemm_kernel(const float* __restrict__ X, const float* __restrict__ Wx,
                    const float* __restrict__ bh, float* __restrict__ out)
{
    __shared__ float As[16][68];
    __shared__ float Bs[16][68];
    const int m0 = blockIdx.x * 64;
    const int n0 = blockIdx.y * 64;
    const int tid = threadIdx.x;
    const int tr = tid >> 4, tc = tid & 15;
    const int lrow = tid >> 2;
    const int lkk  = (tid & 3) * 4;

    float acc[4][4] = {};

    for (int k0 = 0; k0 < D_SZ; k0 += 16) {
        float4 av = *(const float4*)(X  + (size_t)(m0 + lrow) * D_SZ + k0 + lkk);
        float4 bv = *(const float4*)(Wx + (size_t)(n0 + lrow) * D_SZ + k0 + lkk);
        As[lkk+0][lrow] = av.x; As[lkk+1][lrow] = av.y;
        As[lkk+2][lrow] = av.z; As[lkk+3][lrow] = av.w;
        Bs[lkk+0][lrow] = bv.x; Bs[lkk+1][lrow] = bv.y;
        Bs[lkk+2][lrow] = bv.z; Bs[lkk+3][lrow] = bv.w;
        __syncthreads();
        #pragma unroll
        for (int kk = 0; kk < 16; ++kk) {
            float a[4], b[4];
            #pragma unroll
            for (int i = 0; i < 4; ++i) a[i] = As[kk][tr*4+i];
            #pragma unroll
            for (int j = 0; j < 4; ++j) b[j] = Bs[kk][tc*4+j];
            #pragma unroll
            for (int i = 0; i < 4; ++i)
                #pragma unroll
                for (int j = 0; j < 4; ++j)
                    acc[i][j] = fmaf(a[i], b[j], acc[i][j]);
        }
        __syncthreads();
    }
    #pragma unroll
    for (int i = 0; i < 4; ++i) {
        const int m = m0 + tr*4 + i;
        const int n = n0 + tc*4;
        float4 o;
        o.x = acc[i][0] + bh[n+0];
        o.y = acc[i][1] + bh[n+1];
        o.z = acc[i][2] + bh[n+2];
        o.w = acc[i][3] + bh[n+3];
        *(float4*)(out + (size_t)m * D_SZ + n) = o;
    }
}

// ---------------------------------------------------------------------------
// Kernel 2: d-sliced recurrence, self-tagged-pair sync, REGISTER-resident
// weights (each thread holds rows {g16,g16+16} x its 32 k-columns of both
// W_h and W_write = 128 VGPRs). LDS holds only the 8KB tape slice + h.
// ---------------------------------------------------------------------------
__global__ __launch_bounds__(256, 1)
void recurrence_mw(const float* __restrict__ tape0, const float* __restrict__ h0,
                   const float* __restrict__ W_h, const float* __restrict__ W_w,
                   float* __restrict__ out)
{
    __shared__ float tp[NSLOT][TP];    // 9,216 B (tape d-slice)
    __shared__ float hh[D_SZ];         // 2,048 B
    __shared__ float ps_l[NSLOT];
    __shared__ float attn[NSLOT];
    __shared__ float zmv[RPW];
    __shared__ float rp8[8][RPW];

    const int blk = blockIdx.x;
    const int xcd = blk & 7;
    const int jj0 = blk >> 3;
    const int b   = xcd * 2 + (jj0 & 1);
    const int w   = jj0 >> 1;
    const int R0  = w * RPW;
    const int tid = threadIdx.x;
    const int fb  = b * NW;
    const int g16 = tid >> 4, sj = tid & 15;  // matvec layout: 16 lanes per row

    // ---- zero own pair slots (replay safety; 0 never matches tag>=1) ----
    if (tid < NSLOT) AS(&g_ps2[(size_t)(fb + w) * NSLOT + tid], 0ULL);
    if (tid < RPW)   AS(&g_hx2[(size_t)b * D_SZ + R0 + tid], 0ULL);

    // ---- weight slices into REGISTERS (once) ----
    float4 wh0[8], wh1[8], ww0[8], ww1[8];
    {
        const float* a0 = W_h + (size_t)(R0 + g16)      * D_SZ + 4 * sj;
        const float* a1 = W_h + (size_t)(R0 + g16 + 16) * D_SZ + 4 * sj;
        const float* b0 = W_w + (size_t)(R0 + g16)      * D_SZ + 4 * sj;
        const float* b1 = W_w + (size_t)(R0 + g16 + 16) * D_SZ + 4 * sj;
        #pragma unroll
        for (int i = 0; i < 8; ++i) {
            wh0[i] = *(const float4*)(a0 + 64 * i);
            wh1[i] = *(const float4*)(a1 + 64 * i);
            ww0[i] = *(const float4*)(b0 + 64 * i);
            ww1[i] = *(const float4*)(b1 + 64 * i);
        }
    }

    // ---- tape slice + h into LDS ----
    for (int i = tid; i < NSLOT * RPW; i += 256) {
        const int s = i >> 5, jc = i & 31;
        tp[s][jc] = tape0[((size_t)b * NSLOT + s) * D_SZ + R0 + jc];
    }
    for (int i = tid; i < D_SZ; i += 256) hh[i] = h0[(size_t)b * D_SZ + i];
    __syncthreads();

    float* outb = out + (size_t)b * T_SZ * D_SZ;

    const int sA = tid >> 2, qA = tid & 3;    // 4 threads per slot (scores)
    const int jB = tid & 31, sg = tid >> 5;   // read-partials: 8 slot-groups

    for (int t = 0; t < T_SZ; ++t) {
        const unsigned tg = (unsigned)(t + 1);
        float xwv = 0.f;
        if (tid < RPW) xwv = outb[(size_t)t * D_SZ + R0 + tid];

        // ---- A1: local partial scores over our 32 d's ----
        {
            float4 t0 = *(const float4*)&tp[sA][qA * 8];
            float4 t1 = *(const float4*)&tp[sA][qA * 8 + 4];
            float4 ha = *(const float4*)&hh[R0 + qA * 8];
            float4 hb = *(const float4*)&hh[R0 + qA * 8 + 4];
            float acc = t0.x*ha.x + t0.y*ha.y + t0.z*ha.z + t0.w*ha.w
                      + t1.x*hb.x + t1.y*hb.y + t1.z*hb.z + t1.w*hb.w;
            acc += __shfl_xor(acc, 1);
            acc += __shfl_xor(acc, 2);
            if (qA == 0) ps_l[sA] = acc;
        }
        __syncthreads();

        // ---- A2: publish tagged partial scores ----
        if (tid < NSLOT)
            AS(&g_ps2[(size_t)(fb + w) * NSLOT + tid], pk(ps_l[tid], tg));

        // ---- B2: zm = W_h . h from REGISTERS — overlaps score propagation ----
        {
            float a0 = 0.f, a1 = 0.f;
            #pragma unroll
            for (int i = 0; i < 8; ++i) {
                float4 hr = *(const float4*)&hh[4 * sj + 64 * i];
                a0 = fmaf(wh0[i].x, hr.x, a0);
                a0 = fmaf(wh0[i].y, hr.y, a0);
                a0 = fmaf(wh0[i].z, hr.z, a0);
                a0 = fmaf(wh0[i].w, hr.w, a0);
                a1 = fmaf(wh1[i].x, hr.x, a1);
                a1 = fmaf(wh1[i].y, hr.y, a1);
                a1 = fmaf(wh1[i].z, hr.z, a1);
                a1 = fmaf(wh1[i].w, hr.w, a1);
            }
            a0 += __shfl_xor(a0, 1); a1 += __shfl_xor(a1, 1);
            a0 += __shfl_xor(a0, 2); a1 += __shfl_xor(a1, 2);
            a0 += __shfl_xor(a0, 4); a1 += __shfl_xor(a1, 4);
            a0 += __shfl_xor(a0, 8); a1 += __shfl_xor(a1, 8);
            if (sj == 0) { zmv[g16] = a0; zmv[g16 + 16] = a1; }
        }

        // ---- poll 4 score pairs (w' = 4*qA..4*qA+3, slot sA); sum on match ----
        {
            const unsigned long long* pp = &g_ps2[(size_t)(fb + qA * 4) * NSLOT + sA];
            unsigned long long v0, v1, v2, v3;
            for (;;) {
                v0 = AL(pp + 0 * NSLOT); v1 = AL(pp + 1 * NSLOT);
                v2 = AL(pp + 2 * NSLOT); v3 = AL(pp + 3 * NSLOT);
                if ((unsigned)(v0 >> 32) == tg && (unsigned)(v1 >> 32) == tg &&
                    (unsigned)(v2 >> 32) == tg && (unsigned)(v3 >> 32) == tg) break;
                __builtin_amdgcn_s_sleep(1);
            }
            float acc = __uint_as_float((unsigned)v0) + __uint_as_float((unsigned)v1)
                      + __uint_as_float((unsigned)v2) + __uint_as_float((unsigned)v3);
            acc += __shfl_xor(acc, 1);
            acc += __shfl_xor(acc, 2);
            if (qA == 0) ps_l[sA] = acc * SCALE;
        }
        __syncthreads();

        // ---- softmax over 64 slots (wave 0) ----
        if (tid < 64) {
            const float v = ps_l[tid];
            float m = v;
            #pragma unroll
            for (int o = 32; o; o >>= 1) m = fmaxf(m, __shfl_xor(m, o));
            const float e = __expf(v - m);
            float s = e;
            #pragma unroll
            for (int o = 32; o; o >>= 1) s += __shfl_xor(s, o);
            attn[tid] = e / s;
        }
        __syncthreads();

        // ---- B: read partials over our d-slice ----
        {
            float acc = 0.f;
            #pragma unroll
            for (int s8 = 0; s8 < 8; ++s8)
                acc = fmaf(attn[sg * 8 + s8], tp[sg * 8 + s8][jB], acc);
            rp8[sg][jB] = acc;
        }
        __syncthreads();

        // ---- C: h_new own rows; publish tagged pairs ----
        if (tid < RPW) {
            const float rr = rp8[0][tid] + rp8[1][tid] + rp8[2][tid] + rp8[3][tid]
                           + rp8[4][tid] + rp8[5][tid] + rp8[6][tid] + rp8[7][tid];
            const float v = tanhf(zmv[tid] + rr + xwv);
            outb[(size_t)t * D_SZ + R0 + tid] = v;
            AS(&g_hx2[(size_t)b * D_SZ + R0 + tid], pk(v, tg));
        }

        // ---- C2: poll own two h pairs, fill hh ----
        {
            const int d0 = tid * 2;
            const unsigned long long* hp = &g_hx2[(size_t)b * D_SZ + d0];
            unsigned long long v0, v1;
            for (;;) {
                v0 = AL(hp); v1 = AL(hp + 1);
                if ((unsigned)(v0 >> 32) == tg && (unsigned)(v1 >> 32) == tg) break;
                __builtin_amdgcn_s_sleep(1);
            }
            hh[d0]     = __uint_as_float((unsigned)v0);
            hh[d0 + 1] = __uint_as_float((unsigned)v1);
        }
        __syncthreads();

        // ---- D: w_vec rows from REGISTER weights -> tape slot ----
        {
            const int slot = t & (NSLOT - 1);
            float a0 = 0.f, a1 = 0.f;
            #pragma unroll
            for (int i = 0; i < 8; ++i) {
                float4 hr = *(const float4*)&hh[4 * sj + 64 * i];
                a0 = fmaf(ww0[i].x, hr.x, a0);
                a0 = fmaf(ww0[i].y, hr.y, a0);
                a0 = fmaf(ww0[i].z, hr.z, a0);
                a0 = fmaf(ww0[i].w, hr.w, a0);
                a1 = fmaf(ww1[i].x, hr.x, a1);
                a1 = fmaf(ww1[i].y, hr.y, a1);
                a1 = fmaf(ww1[i].z, hr.z, a1);
                a1 = fmaf(ww1[i].w, hr.w, a1);
            }
            a0 += __shfl_xor(a0, 1); a1 += __shfl_xor(a1, 1);
            a0 += __shfl_xor(a0, 2); a1 += __shfl_xor(a1, 2);
            a0 += __shfl_xor(a0, 4); a1 += __shfl_xor(a1, 4);
            a0 += __shfl_xor(a0, 8); a1 += __shfl_xor(a1, 8);
            if (sj == 0) {
                tp[slot][g16]      = a0;
                tp[slot][g16 + 16] = a1;
            }
        }
        __syncthreads();
    }

    // ---- epilogue: tape slice + last-h slice ----
    float* tout = out + (size_t)B_SZ * T_SZ * D_SZ + (size_t)b * NSLOT * D_SZ;
    for (int i = tid; i < NSLOT * RPW; i += 256) {
        const int s = i >> 5, jc = i & 31;
        tout[(size_t)s * D_SZ + R0 + jc] = tp[s][jc];
    }
    if (tid < RPW) {
        float* lout = out + (size_t)B_SZ * T_SZ * D_SZ
                          + (size_t)B_SZ * NSLOT * D_SZ + (size_t)b * D_SZ;
        lout[R0 + tid] = hh[R0 + tid];
    }
}

// ---------------------------------------------------------------------------
extern "C" void kernel_launch(void* const* d_in, const int* in_sizes, int n_in,
                              void* d_out, int out_size, void* d_ws, size_t ws_size,
                              hipStream_t stream)
{
    const float* x_seq   = (const float*)d_in[0];
    const float* h_tape  = (const float*)d_in[1];
    const float* h_work  = (const float*)d_in[2];
    const float* W_h     = (const float*)d_in[3];
    const float* W_x     = (const float*)d_in[4];
    const float* b_h     = (const float*)d_in[5];
    const float* W_write = (const float*)d_in[6];
    float* out = (float*)d_out;

    dim3 g1(T_SZ * B_SZ / 64, D_SZ / 64);
    xw_gemm_kernel<<<g1, 256, 0, stream>>>(x_seq, W_x, b_h, out);

    recurrence_mw<<<B_SZ * NW, 256, 0, stream>>>(h_tape, h_work, W_h, W_write, out);
}